// Round 6
// baseline (886.677 us; speedup 1.0000x reference)
//
#include <hip/hip_runtime.h>

typedef short s16x8 __attribute__((ext_vector_type(8)));
typedef unsigned short u16;
typedef u16 u16x8 __attribute__((ext_vector_type(8)));
typedef u16 u16x4 __attribute__((ext_vector_type(4)));
typedef float f32x4 __attribute__((ext_vector_type(4)));

#define DEVINL __device__ __forceinline__

DEVINL u16 f2bf(float f) {
    unsigned u = __float_as_uint(f);
    u += 0x7FFFu + ((u >> 16) & 1u);
    return (u16)(u >> 16);
}
DEVINL float bf2f(u16 h) { return __uint_as_float((unsigned)h << 16); }

DEVINL void gl2lds16(const void* g, void* l) {
    __builtin_amdgcn_global_load_lds((const __attribute__((address_space(1))) void*)g,
                                     (__attribute__((address_space(3))) void*)l, 16, 0, 0);
}

DEVINL f32x4 mfma16(s16x8 a, s16x8 b, f32x4 c) {
    return __builtin_amdgcn_mfma_f32_16x16x32_bf16(a, b, c, 0, 0, 0);
}

// ---------------------------------------------------------------------------
// Transpose-cast: src (K,N) fp32 row-major -> dst (N,K) bf16 row-major
// ---------------------------------------------------------------------------
__global__ __launch_bounds__(256) void tcast(
    const float* __restrict__ src, u16* __restrict__ dst, const int K, const int N)
{
    __shared__ float tile[32][33];
    const long k0 = (long)blockIdx.x * 32;
    const long n0 = (long)blockIdx.y * 32;
    const int tid = threadIdx.x;
    const int r = tid >> 3, c4 = (tid & 7) * 4;
    float4 v = *(const float4*)&src[(k0 + r) * N + n0 + c4];
    tile[r][c4] = v.x; tile[r][c4 + 1] = v.y; tile[r][c4 + 2] = v.z; tile[r][c4 + 3] = v.w;
    __syncthreads();
    u16x4 ov;
    ov[0] = f2bf(tile[c4][r]);     ov[1] = f2bf(tile[c4 + 1][r]);
    ov[2] = f2bf(tile[c4 + 2][r]); ov[3] = f2bf(tile[c4 + 3][r]);
    *(u16x4*)&dst[(n0 + r) * K + k0 + c4] = ov;
}

// ---------------------------------------------------------------------------
// RMSNorm (C=2048) fp32 -> bf16
// ---------------------------------------------------------------------------
__global__ __launch_bounds__(256) void rmsnorm_cast(
    const float* __restrict__ x, const float* __restrict__ wn, u16* __restrict__ out)
{
    const int C = 2048;
    const long row = blockIdx.x;
    const int tid = threadIdx.x;
    const float4* xr = (const float4*)(x + row * C);
    float4 a = xr[tid * 2], b = xr[tid * 2 + 1];
    float ss = a.x*a.x + a.y*a.y + a.z*a.z + a.w*a.w
             + b.x*b.x + b.y*b.y + b.z*b.z + b.w*b.w;
#pragma unroll
    for (int m = 1; m < 64; m <<= 1) ss += __shfl_xor(ss, m);
    __shared__ float red[4];
    if ((tid & 63) == 0) red[tid >> 6] = ss;
    __syncthreads();
    float scale = rsqrtf((red[0] + red[1] + red[2] + red[3]) * (1.f / 2048.f) + 1e-6f);
    const float4* wr = (const float4*)wn;
    float4 wa = wr[tid * 2], wb = wr[tid * 2 + 1];
    u16x8 o;
    o[0] = f2bf(a.x * scale * wa.x); o[1] = f2bf(a.y * scale * wa.y);
    o[2] = f2bf(a.z * scale * wa.z); o[3] = f2bf(a.w * scale * wa.w);
    o[4] = f2bf(b.x * scale * wb.x); o[5] = f2bf(b.y * scale * wb.y);
    o[6] = f2bf(b.z * scale * wb.z); o[7] = f2bf(b.w * scale * wb.w);
    *(u16x8*)&out[row * C + tid * 8] = o;
}

// ---------------------------------------------------------------------------
// GEMM, wave-retiled: 128x128 block, 128 thr (2 waves), wave tile 128x64.
// 24 ds_read_b128 per 64 MFMA per wave per K-tile (0.375 ratio, m201 geometry).
// Single-buffered LDS, 2 barriers/K-tile, XOR source-swizzle (round-0 skeleton).
// Staging: one base pointer/operand; rows step 16 per round (16 % 8 == 0 so
// the XOR'd column is round-invariant); LDS dest = tid*16 + rr*2048.
// MODE 0: outB = bf16(acc)   MODE 1: outF = resid + acc (fp32)
// ---------------------------------------------------------------------------
template <int MODE>
__global__ __launch_bounds__(128, 2) void gemmW(
    const u16* __restrict__ A, const u16* __restrict__ Bt,
    const int N, const int K,
    float* __restrict__ outF, u16* __restrict__ outB,
    const float* __restrict__ resid)
{
    __shared__ u16 As[128 * 64];
    __shared__ u16 Bs[128 * 64];
    const int tid = threadIdx.x;
    const int lane = tid & 63;
    const int w = tid >> 6;              // wn: 0..1, wave tile 128 x 64
    const int quad = lane >> 4, l16 = lane & 15;
    const int asw = l16 & 7;
    const long m0 = (long)blockIdx.x * 128;
    const long n0 = (long)blockIdx.y * 128;

    const int r0 = tid >> 3;                       // 0..15
    const int c0 = ((tid & 7) ^ (r0 & 7)) * 8;     // XOR source-swizzle col
    const u16* gA = A + (m0 + r0) * K + c0;
    const u16* gB = Bt + (n0 + r0) * K + c0;
    char* lA = (char*)As + tid * 16;
    char* lB = (char*)Bs + tid * 16;
    const long rstep = (long)16 * K;               // 16 rows per round

    f32x4 acc[8][4] = {};

    for (int k0 = 0; k0 < K; k0 += 64) {
#pragma unroll
        for (int rr = 0; rr < 8; ++rr)
            gl2lds16(gA + k0 + rr * rstep, lA + rr * 2048);
#pragma unroll
        for (int rr = 0; rr < 8; ++rr)
            gl2lds16(gB + k0 + rr * rstep, lB + rr * 2048);
        __syncthreads();
#pragma unroll
        for (int ks = 0; ks < 2; ++ks) {
            const int csel = ((ks * 4 + quad) ^ asw) * 8;
            s16x8 b[4];
#pragma unroll
            for (int nt = 0; nt < 4; ++nt)
                b[nt] = *(const s16x8*)&Bs[(w * 64 + nt * 16 + l16) * 64 + csel];
#pragma unroll
            for (int mh = 0; mh < 2; ++mh) {
                s16x8 a[4];
#pragma unroll
                for (int mt = 0; mt < 4; ++mt)
                    a[mt] = *(const s16x8*)&As[((mh * 4 + mt) * 16 + l16) * 64 + csel];
#pragma unroll
                for (int mt = 0; mt < 4; ++mt)
#pragma unroll
                    for (int nt = 0; nt < 4; ++nt)
                        acc[mh * 4 + mt][nt] = mfma16(a[mt], b[nt], acc[mh * 4 + mt][nt]);
            }
        }
        __syncthreads();
    }

#pragma unroll
    for (int mtg = 0; mtg < 8; ++mtg)
#pragma unroll
        for (int reg = 0; reg < 4; ++reg) {
            long row = m0 + mtg * 16 + quad * 4 + reg;
#pragma unroll
            for (int nt = 0; nt < 4; ++nt) {
                long col = n0 + w * 64 + nt * 16 + l16;
                float v = acc[mtg][nt][reg];
                if (MODE == 0) {
                    outB[row * N + col] = f2bf(v);
                } else {
                    outF[row * N + col] = resid[row * N + col] + v;
                }
            }
        }
}

// ---------------------------------------------------------------------------
// Fused FFN up-projection, wave-retiled: 128x128 block, 256 thr (4 waves,
// 1M x 4N), wave tile 128x32 with DUAL accumulators (64+64 = 128 VGPR).
// 24 ds_read_b128 per 64 MFMA per wave per K-tile (0.375 ratio).
// u = bf16( silu(A@B1t^T) * (A@B2t^T) )
// ---------------------------------------------------------------------------
__global__ __launch_bounds__(256, 2) void gemmFFNW(
    const u16* __restrict__ A, const u16* __restrict__ B1t, const u16* __restrict__ B2t,
    const int N, const int K, u16* __restrict__ outB)
{
    __shared__ u16 As[128 * 64];
    __shared__ u16 B1s[128 * 64];
    __shared__ u16 B2s[128 * 64];
    const int tid = threadIdx.x;
    const int lane = tid & 63;
    const int w = tid >> 6;              // wn: 0..3, wave tile 128 x 32
    const int quad = lane >> 4, l16 = lane & 15;
    const int asw = l16 & 7;
    const long m0 = (long)blockIdx.x * 128;
    const long n0 = (long)blockIdx.y * 128;

    const int r0 = tid >> 3;                       // 0..31
    const int c0 = ((tid & 7) ^ (r0 & 7)) * 8;
    const u16* gA  = A   + (m0 + r0) * K + c0;
    const u16* gB1 = B1t + (n0 + r0) * K + c0;
    const u16* gB2 = B2t + (n0 + r0) * K + c0;
    char* lA  = (char*)As  + tid * 16;
    char* lB1 = (char*)B1s + tid * 16;
    char* lB2 = (char*)B2s + tid * 16;
    const long rstep = (long)32 * K;               // 32 rows per round

    f32x4 acc1[8][2] = {};
    f32x4 acc2[8][2] = {};

    for (int k0 = 0; k0 < K; k0 += 64) {
#pragma unroll
        for (int rr = 0; rr < 4; ++rr)
            gl2lds16(gA + k0 + rr * rstep, lA + rr * 4096);
#pragma unroll
        for (int rr = 0; rr < 4; ++rr)
            gl2lds16(gB1 + k0 + rr * rstep, lB1 + rr * 4096);
#pragma unroll
        for (int rr = 0; rr < 4; ++rr)
            gl2lds16(gB2 + k0 + rr * rstep, lB2 + rr * 4096);
        __syncthreads();
#pragma unroll
        for (int ks = 0; ks < 2; ++ks) {
            const int csel = ((ks * 4 + quad) ^ asw) * 8;
            s16x8 b1[2], b2[2];
#pragma unroll
            for (int nt = 0; nt < 2; ++nt) {
                b1[nt] = *(const s16x8*)&B1s[(w * 32 + nt * 16 + l16) * 64 + csel];
                b2[nt] = *(const s16x8*)&B2s[(w * 32 + nt * 16 + l16) * 64 + csel];
            }
#pragma unroll
            for (int mh = 0; mh < 2; ++mh) {
                s16x8 a[4];
#pragma unroll
                for (int mt = 0; mt < 4; ++mt)
                    a[mt] = *(const s16x8*)&As[((mh * 4 + mt) * 16 + l16) * 64 + csel];
#pragma unroll
                for (int mt = 0; mt < 4; ++mt)
#pragma unroll
                    for (int nt = 0; nt < 2; ++nt) {
                        acc1[mh * 4 + mt][nt] = mfma16(a[mt], b1[nt], acc1[mh * 4 + mt][nt]);
                        acc2[mh * 4 + mt][nt] = mfma16(a[mt], b2[nt], acc2[mh * 4 + mt][nt]);
                    }
            }
        }
        __syncthreads();
    }

#pragma unroll
    for (int mtg = 0; mtg < 8; ++mtg)
#pragma unroll
        for (int reg = 0; reg < 4; ++reg) {
            long row = m0 + mtg * 16 + quad * 4 + reg;
#pragma unroll
            for (int nt = 0; nt < 2; ++nt) {
                long col = n0 + w * 32 + nt * 16 + l16;
                float g = acc1[mtg][nt][reg];
                float s = g / (1.f + __expf(-g));
                outB[row * N + col] = f2bf(s * acc2[mtg][nt][reg]);
            }
        }
}

// ---------------------------------------------------------------------------
// RoPE, vectorized: one block per (b,t) row; q scaled by 1/sqrt(D).
// qkv (B*T, 6144) bf16 -> qT/kT [bh][t][d]
// ---------------------------------------------------------------------------
__global__ __launch_bounds__(256) void rope_qk(
    const u16* __restrict__ qkv, u16* __restrict__ qT, u16* __restrict__ kT)
{
    const int row = blockIdx.x;
    const int t = row & 2047, b = row >> 11;
    const int tid = threadIdx.x;
    __shared__ u16 buf[4096];
    const u16* src = qkv + (long)row * 6144;
    u16x8 aa = *(const u16x8*)&src[tid * 8];
    u16x8 kk = *(const u16x8*)&src[2048 + tid * 8];
    *(u16x8*)&buf[tid * 8] = aa;
    *(u16x8*)&buf[2048 + tid * 8] = kk;
    __syncthreads();
    const int c = tid * 8;
    const int h = c >> 7, dh = c & 127;
    const bool first = dh < 64;
    const int pc = first ? (c + 64) : (c - 64);
    float cs[8], sn[8];
#pragma unroll
    for (int j = 0; j < 8; ++j) {
        float inv = __expf(-(float)((dh & 63) + j) * 0.14391156831212787f); // ln(1e4)/64
        float ang = (float)t * inv;
        cs[j] = cosf(ang); sn[j] = sinf(ang);
    }
    const long obase = ((long)(b * 16 + h) * 2048 + t) * 128 + dh;
#pragma unroll
    for (int part = 0; part < 2; ++part) {
        const int base = part * 2048;
        u16x8 mine = *(const u16x8*)&buf[base + c];
        u16x8 oth  = *(const u16x8*)&buf[base + pc];
        const float qs = part ? 1.f : 0.08838834764831845f;
        u16x8 o;
#pragma unroll
        for (int j = 0; j < 8; ++j) {
            float xv = bf2f(mine[j]), yv = bf2f(oth[j]);
            float ov = first ? (xv * cs[j] - yv * sn[j]) : (yv * sn[j] + xv * cs[j]);
            o[j] = f2bf(ov * qs);
        }
        u16* dst = part ? kT : qT;
        *(u16x8*)&dst[obase] = o;
    }
}

// ---------------------------------------------------------------------------
// v transpose: qkv v-part (b,t)(h,d) -> vT [bh][d][t].  LDS stride 65 (odd).
// ---------------------------------------------------------------------------
__global__ __launch_bounds__(256) void vtrans(
    const u16* __restrict__ qkv, u16* __restrict__ vT)
{
    const int bh = blockIdx.x;
    const int b = bh >> 4, h = bh & 15;
    const int t0 = blockIdx.y * 64, d0 = blockIdx.z * 64;
    __shared__ u16 tile[64 * 65];
    const int tid = threadIdx.x;
#pragma unroll
    for (int rr = 0; rr < 2; ++rr) {
        int idx = rr * 256 + tid;
        int r = idx >> 3, c = (idx & 7) * 8;
        u16x8 v = *(const u16x8*)&qkv[(long)(b * 2048 + t0 + r) * 6144 + 4096 + h * 128 + d0 + c];
#pragma unroll
        for (int j = 0; j < 8; ++j) tile[r * 65 + c + j] = v[j];
    }
    __syncthreads();
#pragma unroll
    for (int rr = 0; rr < 2; ++rr) {
        int idx = rr * 256 + tid;
        int dd = idx >> 3, cc = (idx & 7) * 8;
        u16x8 o;
#pragma unroll
        for (int j = 0; j < 8; ++j) o[j] = tile[(cc + j) * 65 + dd];
        *(u16x8*)&vT[((long)bh * 128 + d0 + dd) * 2048 + t0 + cc] = o;
    }
}

// ---------------------------------------------------------------------------
// Flash attention, causal. 1D grid 1024 blocks, 256 thr (4 waves, 16 q-rows
// each, QBLK=64). XCD-chunked swizzle (4 bh per XCD, heavy-qt-first).
// Double-buffered K/V, XOR-swizzled LDS, q pre-scaled by 1/sqrt(D).
// T13 defer-max + T5 setprio.
// ---------------------------------------------------------------------------
__global__ __launch_bounds__(256, 2) void attn_kernel(
    const u16* __restrict__ qT, const u16* __restrict__ kT,
    const u16* __restrict__ vT, u16* __restrict__ outT)
{
    const int T = 2048, D = 128;
    const int lid = blockIdx.x;
    const int swz = (lid & 7) * 128 + (lid >> 3);   // nwg=1024, chunk=128
    const int bh = swz >> 5;                        // 4 consecutive bh per XCD
    const int qt = 31 - (swz & 31);                 // heavy q-tiles first
    const int tid = threadIdx.x, lane = tid & 63, w = tid >> 6;
    const int quad = lane >> 4, l16 = lane & 15;
    const int qrow = qt * 64 + w * 16;

    __shared__ u16 Ks[2][64 * 128];
    __shared__ u16 Vs[2][128 * 64];
    __shared__ u16 Ps[4][16 * 64];

    s16x8 aq[4];
    const u16* qb = qT + ((long)bh * T + qrow + l16) * D;
#pragma unroll
    for (int kk = 0; kk < 4; ++kk)
        aq[kk] = *(const s16x8*)&qb[kk * 32 + quad * 8];

    f32x4 o[8] = {};
    float mi[4] = {-INFINITY, -INFINITY, -INFINITY, -INFINITY};
    float li[4] = {0.f, 0.f, 0.f, 0.f};

    const u16* kg0 = kT + (long)bh * T * D;
    const u16* vg0 = vT + (long)bh * D * T;

    auto stage = [&](int kt, int b) {
        const int k0 = kt * 64;
#pragma unroll
        for (int rr = 0; rr < 4; ++rr) {
            int idx = rr * 256 + tid;
            int kr = idx >> 4, kj = idx & 15;
            gl2lds16(kg0 + (long)(k0 + kr) * D + ((kj ^ (kr & 15)) * 8),
                     (char*)Ks[b] + idx * 16);
            int vr = idx >> 3, vj = idx & 7;
            gl2lds16(vg0 + (long)vr * T + k0 + ((vj ^ (vr & 7)) * 8),
                     (char*)Vs[b] + idx * 16);
        }
    };

    stage(0, 0);

    for (int kt = 0; kt <= qt; ++kt) {
        __syncthreads();                 // buf[kt&1] ready (loads had 1 full iter)
        if (kt < qt) stage(kt + 1, (kt + 1) & 1);
        const u16* ks_ = Ks[kt & 1];
        const u16* vs_ = Vs[kt & 1];
        const int k0 = kt * 64;

        // S = Q K^T
        f32x4 sf[4] = {};
        __builtin_amdgcn_s_setprio(1);
#pragma unroll
        for (int kk = 0; kk < 4; ++kk) {
#pragma unroll
            for (int nt = 0; nt < 4; ++nt) {
                s16x8 kb = *(const s16x8*)&ks_[(nt * 16 + l16) * 128 +
                                               ((kk * 4 + quad) ^ (l16 & 15)) * 8];
                sf[nt] = __builtin_amdgcn_mfma_f32_16x16x32_bf16(aq[kk], kb, sf[nt], 0, 0, 0);
            }
        }
        __builtin_amdgcn_s_setprio(0);

        float S[4][4];
        if (kt == qt) {   // diagonal tile: causal mask
#pragma unroll
            for (int nt = 0; nt < 4; ++nt) {
                int col = k0 + nt * 16 + l16;
#pragma unroll
                for (int reg = 0; reg < 4; ++reg) {
                    int row = qrow + quad * 4 + reg;
                    S[nt][reg] = (col <= row) ? sf[nt][reg] : -INFINITY;
                }
            }
        } else {
#pragma unroll
            for (int nt = 0; nt < 4; ++nt)
#pragma unroll
                for (int reg = 0; reg < 4; ++reg)
                    S[nt][reg] = sf[nt][reg];
        }

        float rm[4];
#pragma unroll
        for (int reg = 0; reg < 4; ++reg)
            rm[reg] = fmaxf(fmaxf(S[0][reg], S[1][reg]), fmaxf(S[2][reg], S[3][reg]));
#pragma unroll
        for (int m = 1; m < 16; m <<= 1)
#pragma unroll
            for (int reg = 0; reg < 4; ++reg)
                rm[reg] = fmaxf(rm[reg], __shfl_xor(rm[reg], m));

        // T13 defer-max: only rescale when the running max grew by > 8
        int cond = 1;
#pragma unroll
        for (int reg = 0; reg < 4; ++reg)
            cond &= (rm[reg] - mi[reg] <= 8.f) ? 1 : 0;
        if (!__all(cond)) {
            float alpha[4];
#pragma unroll
            for (int reg = 0; reg < 4; ++reg) {
                float mn = fmaxf(mi[reg], rm[reg]);
                alpha[reg] = __expf(mi[reg] - mn);
                mi[reg] = mn;
                li[reg] *= alpha[reg];
            }
#pragma unroll
            for (int dt = 0; dt < 8; ++dt)
#pragma unroll
                for (int reg = 0; reg < 4; ++reg)
                    o[dt][reg] *= alpha[reg];
        }

        float rs[4] = {};
#pragma unroll
        for (int nt = 0; nt < 4; ++nt)
#pragma unroll
            for (int reg = 0; reg < 4; ++reg) {
                float p = __expf(S[nt][reg] - mi[reg]);
                S[nt][reg] = p;
                rs[reg] += p;
            }
#pragma unroll
        for (int m = 1; m < 16; m <<= 1)
#pragma unroll
            for (int reg = 0; reg < 4; ++reg)
                rs[reg] += __shfl_xor(rs[reg], m);
#pragma unroll
        for (int reg = 0; reg < 4; ++reg)
            li[reg] += rs[reg];

        // P -> LDS, wave-private region (no barrier needed), XOR-swizzled
#pragma unroll
        for (int nt = 0; nt < 4; ++nt)
#pragma unroll
            for (int reg = 0; reg < 4; ++reg) {
                int prow = quad * 4 + reg;
                int pcol = nt * 16 + l16;
                Ps[w][prow * 64 + (((pcol >> 3) ^ (prow & 7)) * 8) + (pcol & 7)]
                    = f2bf(S[nt][reg]);
            }

        // O += P V   (Ps read: row l16, chunk ks*4+quad, swizzled)
        __builtin_amdgcn_s_setprio(1);
#pragma unroll
        for (int ks = 0; ks < 2; ++ks) {
            s16x8 pa = *(const s16x8*)&Ps[w][l16 * 64 +
                                             ((ks * 4 + quad) ^ (l16 & 7)) * 8];
#pragma unroll
            for (int dt = 0; dt < 8; ++dt) {
                s16x8 vb = *(const s16x8*)&vs_[(dt * 16 + l16) * 64 +
                                               ((ks * 4 + quad) ^ (l16 & 7)) * 8];
                o[dt] = __builtin_amdgcn_mfma_f32_16x16x32_bf16(pa, vb, o[dt], 0, 0, 0);
            }
        }
        __builtin_amdgcn_s_setprio(0);
    }

    const int b = bh >> 4, h = bh & 15;
#pragma unroll
    for (int reg = 0; reg < 4; ++reg) {
        float inv = 1.f / li[reg];
        int t = qrow + quad * 4 + reg;
        u16* orow = outT + ((long)(b * T + t)) * 2048 + h * 128;
#pragma unroll
        for (int dt = 0; dt < 8; ++dt)
            orow[dt * 16 + l16] = f2bf(o[dt][reg] * inv);
    }
}

// ---------------------------------------------------------------------------
// Workspace layout (188 MiB total, unions by live-range):
//   Z 24 MiB: wqkv_t -> w3_t | wproj 8 | w1_t 22 | w2_t 22
//   C 16 MiB: h -> attn_out -> h2 | D 48 MiB: qkv -> u | E 48 MiB: q/k/vT -> x2
// ---------------------------------------------------------------------------
extern "C" void kernel_launch(void* const* d_in, const int* in_sizes, int n_in,
                              void* d_out, int out_size, void* d_ws, size_t ws_size,
                              hipStream_t stream) {
    const float* x      = (const float*)d_in[0];
    const float* wn1    = (const float*)d_in[1];
    const float* w_qkv  = (const float*)d_in[2];
    const float* w_proj = (const float*)d_in[3];
    const float* wn2    = (const float*)d_in[4];
    const float* w1     = (const float*)d_in[5];
    const float* w2     = (const float*)d_in[6];
    const float* w3     = (const float*)d_in[7];
    float* out = (float*)d_out;

    char* p = (char*)d_ws;
    u16* Z       = (u16*)p; p += (size_t)6144 * 2048 * 2;
    u16* wproj_t = (u16*)p; p += (size_t)2048 * 2048 * 2;
    u16* w1_t    = (u16*)p; p += (size_t)5632 * 2048 * 2;
    u16* w2_t    = (u16*)p; p += (size_t)5632 * 2048 * 2;
    u16* C       = (u16*)p; p += (size_t)4096 * 2048 * 2;
    u16* D       = (u16*)p; p += (size_t)4096 * 6144 * 2;
    u16* E       = (u16*)p; p += (size_t)3 * 32 * 2048 * 128 * 2;

    u16* wqkv_t = Z;
    u16* w3_t   = Z;
    u16* qT = E;
    u16* kT = E + (size_t)32 * 2048 * 128;
    u16* vT = E + (size_t)2 * 32 * 2048 * 128;
    float* x2 = (float*)E;
    u16* uu = D;

    tcast<<<dim3(64, 192), 256, 0, stream>>>(w_qkv, wqkv_t, 2048, 6144);
    tcast<<<dim3(64, 64), 256, 0, stream>>>(w_proj, wproj_t, 2048, 2048);
    tcast<<<dim3(64, 176), 256, 0, stream>>>(w1, w1_t, 2048, 5632);
    tcast<<<dim3(64, 176), 256, 0, stream>>>(w2, w2_t, 2048, 5632);

    rmsnorm_cast<<<4096, 256, 0, stream>>>(x, wn1, C);
    gemmW<0><<<dim3(32, 48), 128, 0, stream>>>(C, wqkv_t, 6144, 2048,
                                               nullptr, D, nullptr);
    rope_qk<<<4096, 256, 0, stream>>>(D, qT, kT);
    vtrans<<<dim3(32, 32, 2), 256, 0, stream>>>(D, vT);

    tcast<<<dim3(176, 64), 256, 0, stream>>>(w3, w3_t, 5632, 2048);

    attn_kernel<<<1024, 256, 0, stream>>>(qT, kT, vT, C);

    gemmW<1><<<dim3(32, 16), 128, 0, stream>>>(C, wproj_t, 2048, 2048,
                                               x2, nullptr, x);
    rmsnorm_cast<<<4096, 256, 0, stream>>>(x2, wn2, C);
    gemmFFNW<<<dim3(32, 44), 256, 0, stream>>>(C, w1_t, w2_t, 5632, 2048, uu);
    gemmW<1><<<dim3(32, 16), 128, 0, stream>>>(uu, w3_t, 2048, 5632,
                                               out, nullptr, x2);
}

// Round 7
// 837.671 us; speedup vs baseline: 1.0585x; 1.0585x over previous
//
#include <hip/hip_runtime.h>

typedef short s16x8 __attribute__((ext_vector_type(8)));
typedef unsigned short u16;
typedef u16 u16x8 __attribute__((ext_vector_type(8)));
typedef u16 u16x4 __attribute__((ext_vector_type(4)));
typedef float f32x4 __attribute__((ext_vector_type(4)));

#define DEVINL __device__ __forceinline__

DEVINL u16 f2bf(float f) {
    unsigned u = __float_as_uint(f);
    u += 0x7FFFu + ((u >> 16) & 1u);
    return (u16)(u >> 16);
}
DEVINL float bf2f(u16 h) { return __uint_as_float((unsigned)h << 16); }

DEVINL void gl2lds16(const void* g, void* l) {
    __builtin_amdgcn_global_load_lds((const __attribute__((address_space(1))) void*)g,
                                     (__attribute__((address_space(3))) void*)l, 16, 0, 0);
}

// ---------------------------------------------------------------------------
// Transpose-cast: src (K,N) fp32 row-major -> dst (N,K) bf16 row-major
// Core tile routine shared by the fused and single variants.
// ---------------------------------------------------------------------------
DEVINL void tcast_tile(const float* __restrict__ src, u16* __restrict__ dst,
                       const int K, const int N, const int kx, const int ny,
                       const int tid, float (*tile)[33])
{
    const long k0 = (long)kx * 32;
    const long n0 = (long)ny * 32;
    const int r = tid >> 3, c4 = (tid & 7) * 4;
    float4 v = *(const float4*)&src[(k0 + r) * N + n0 + c4];
    tile[r][c4] = v.x; tile[r][c4 + 1] = v.y; tile[r][c4 + 2] = v.z; tile[r][c4 + 3] = v.w;
    __syncthreads();
    u16x4 ov;
    ov[0] = f2bf(tile[c4][r]);     ov[1] = f2bf(tile[c4 + 1][r]);
    ov[2] = f2bf(tile[c4 + 2][r]); ov[3] = f2bf(tile[c4 + 3][r]);
    *(u16x4*)&dst[(n0 + r) * K + k0 + c4] = ov;
}

// Fused tcast for the 4 independent weights (all K=2048 -> 64 k-tiles):
// w_qkv (N=6144, 12288 tiles) | w_proj (N=2048, 4096) | w1 (N=5632, 11264)
// | w2 (N=5632, 11264).  One launch, 38912 blocks.
__global__ __launch_bounds__(256) void tcast4(
    const float* __restrict__ s0, const float* __restrict__ s1,
    const float* __restrict__ s2, const float* __restrict__ s3,
    u16* __restrict__ d0, u16* __restrict__ d1,
    u16* __restrict__ d2, u16* __restrict__ d3)
{
    __shared__ float tile[32][33];
    int t = blockIdx.x;
    const float* src; u16* dst; int N;
    if (t < 12288)      {             src = s0; dst = d0; N = 6144; }
    else if (t < 16384) { t -= 12288; src = s1; dst = d1; N = 2048; }
    else if (t < 27648) { t -= 16384; src = s2; dst = d2; N = 5632; }
    else                { t -= 27648; src = s3; dst = d3; N = 5632; }
    tcast_tile(src, dst, 2048, N, t & 63, t >> 6, threadIdx.x, tile);
}

// Single tcast (w3: K=5632, N=2048) — must run after the qkv GEMM since
// w3_t aliases wqkv_t's workspace.
__global__ __launch_bounds__(256) void tcast(
    const float* __restrict__ src, u16* __restrict__ dst, const int K, const int N)
{
    __shared__ float tile[32][33];
    tcast_tile(src, dst, K, N, blockIdx.x, blockIdx.y, threadIdx.x, tile);
}

// ---------------------------------------------------------------------------
// RMSNorm (C=2048) fp32 -> bf16
// ---------------------------------------------------------------------------
__global__ __launch_bounds__(256) void rmsnorm_cast(
    const float* __restrict__ x, const float* __restrict__ wn, u16* __restrict__ out)
{
    const int C = 2048;
    const long row = blockIdx.x;
    const int tid = threadIdx.x;
    const float4* xr = (const float4*)(x + row * C);
    float4 a = xr[tid * 2], b = xr[tid * 2 + 1];
    float ss = a.x*a.x + a.y*a.y + a.z*a.z + a.w*a.w
             + b.x*b.x + b.y*b.y + b.z*b.z + b.w*b.w;
#pragma unroll
    for (int m = 1; m < 64; m <<= 1) ss += __shfl_xor(ss, m);
    __shared__ float red[4];
    if ((tid & 63) == 0) red[tid >> 6] = ss;
    __syncthreads();
    float scale = rsqrtf((red[0] + red[1] + red[2] + red[3]) * (1.f / 2048.f) + 1e-6f);
    const float4* wr = (const float4*)wn;
    float4 wa = wr[tid * 2], wb = wr[tid * 2 + 1];
    u16x8 o;
    o[0] = f2bf(a.x * scale * wa.x); o[1] = f2bf(a.y * scale * wa.y);
    o[2] = f2bf(a.z * scale * wa.z); o[3] = f2bf(a.w * scale * wa.w);
    o[4] = f2bf(b.x * scale * wb.x); o[5] = f2bf(b.y * scale * wb.y);
    o[6] = f2bf(b.z * scale * wb.z); o[7] = f2bf(b.w * scale * wb.w);
    *(u16x8*)&out[row * C + tid * 8] = o;
}

// ---------------------------------------------------------------------------
// GEMM: A (M x K) bf16 row-major, Bt (N x K) bf16 row-major, 128x128 tile.
// LDS tiles XOR-swizzled: chunk j of row r stored at slot j^(r&7).
// MODE 0: outB = bf16(acc)   MODE 1: outF = resid + acc (fp32)
// ---------------------------------------------------------------------------
template <int MODE>
__global__ __launch_bounds__(256, 2) void gemm128(
    const u16* __restrict__ A, const u16* __restrict__ Bt,
    const int N, const int K,
    float* __restrict__ outF, u16* __restrict__ outB,
    const float* __restrict__ resid)
{
    __shared__ u16 As[128 * 64];
    __shared__ u16 Bs[128 * 64];
    const int tid = threadIdx.x;
    const int lane = tid & 63;
    const int w = tid >> 6;
    const int wm = w >> 1, wn = w & 1;
    const int quad = lane >> 4, l16 = lane & 15;
    const long m0 = (long)blockIdx.x * 128;
    const long n0 = (long)blockIdx.y * 128;

    const u16* ga[4]; const u16* gb[4]; char* la[4]; char* lb[4];
#pragma unroll
    for (int rr = 0; rr < 4; ++rr) {
        int idx = rr * 256 + tid;
        int r = idx >> 3, j = idx & 7;
        int c = (j ^ (r & 7)) * 8;          // XOR source-swizzle
        ga[rr] = A + (m0 + r) * K + c;
        gb[rr] = Bt + (n0 + r) * K + c;
        la[rr] = (char*)As + idx * 16;
        lb[rr] = (char*)Bs + idx * 16;
    }

    f32x4 acc[4][4] = {};

    for (int k0 = 0; k0 < K; k0 += 64) {
#pragma unroll
        for (int rr = 0; rr < 4; ++rr) {
            gl2lds16(ga[rr] + k0, la[rr]);
            gl2lds16(gb[rr] + k0, lb[rr]);
        }
        __syncthreads();
#pragma unroll
        for (int ks = 0; ks < 2; ++ks) {
            s16x8 af[4], bfv[4];
#pragma unroll
            for (int mt = 0; mt < 4; ++mt)
                af[mt] = *(const s16x8*)&As[(wm * 64 + mt * 16 + l16) * 64 +
                                            ((ks * 4 + quad) ^ (l16 & 7)) * 8];
#pragma unroll
            for (int nt = 0; nt < 4; ++nt)
                bfv[nt] = *(const s16x8*)&Bs[(wn * 64 + nt * 16 + l16) * 64 +
                                             ((ks * 4 + quad) ^ (l16 & 7)) * 8];
#pragma unroll
            for (int mt = 0; mt < 4; ++mt)
#pragma unroll
                for (int nt = 0; nt < 4; ++nt)
                    acc[mt][nt] = __builtin_amdgcn_mfma_f32_16x16x32_bf16(af[mt], bfv[nt], acc[mt][nt], 0, 0, 0);
        }
        __syncthreads();
    }

#pragma unroll
    for (int mt = 0; mt < 4; ++mt)
#pragma unroll
        for (int reg = 0; reg < 4; ++reg) {
            long row = m0 + wm * 64 + mt * 16 + quad * 4 + reg;
#pragma unroll
            for (int nt = 0; nt < 4; ++nt) {
                long col = n0 + wn * 64 + nt * 16 + l16;
                float v = acc[mt][nt][reg];
                if (MODE == 0) {
                    outB[row * N + col] = f2bf(v);
                } else {
                    outF[row * N + col] = resid[row * N + col] + v;
                }
            }
        }
}

// ---------------------------------------------------------------------------
// Fused FFN up-projection: u = bf16( silu(A@B1t^T) * (A@B2t^T) )
// ---------------------------------------------------------------------------
__global__ __launch_bounds__(256, 2) void gemm_ffn(
    const u16* __restrict__ A, const u16* __restrict__ B1t, const u16* __restrict__ B2t,
    const int N, const int K, u16* __restrict__ outB)
{
    __shared__ u16 As[128 * 64];
    __shared__ u16 B1s[128 * 64];
    __shared__ u16 B2s[128 * 64];
    const int tid = threadIdx.x;
    const int lane = tid & 63;
    const int w = tid >> 6;
    const int wm = w >> 1, wn = w & 1;
    const int quad = lane >> 4, l16 = lane & 15;
    const long m0 = (long)blockIdx.x * 128;
    const long n0 = (long)blockIdx.y * 128;

    const u16* ga[4]; const u16* gb1[4]; const u16* gb2[4];
    char* la[4]; char* lb1[4]; char* lb2[4];
#pragma unroll
    for (int rr = 0; rr < 4; ++rr) {
        int idx = rr * 256 + tid;
        int r = idx >> 3, j = idx & 7;
        int c = (j ^ (r & 7)) * 8;
        ga[rr]  = A + (m0 + r) * K + c;
        gb1[rr] = B1t + (n0 + r) * K + c;
        gb2[rr] = B2t + (n0 + r) * K + c;
        la[rr]  = (char*)As + idx * 16;
        lb1[rr] = (char*)B1s + idx * 16;
        lb2[rr] = (char*)B2s + idx * 16;
    }

    f32x4 acc1[4][4] = {};
    f32x4 acc2[4][4] = {};

    for (int k0 = 0; k0 < K; k0 += 64) {
#pragma unroll
        for (int rr = 0; rr < 4; ++rr) {
            gl2lds16(ga[rr] + k0, la[rr]);
            gl2lds16(gb1[rr] + k0, lb1[rr]);
            gl2lds16(gb2[rr] + k0, lb2[rr]);
        }
        __syncthreads();
#pragma unroll
        for (int ks = 0; ks < 2; ++ks) {
            s16x8 af[4], b1f[4], b2f[4];
#pragma unroll
            for (int mt = 0; mt < 4; ++mt)
                af[mt] = *(const s16x8*)&As[(wm * 64 + mt * 16 + l16) * 64 +
                                            ((ks * 4 + quad) ^ (l16 & 7)) * 8];
#pragma unroll
            for (int nt = 0; nt < 4; ++nt) {
                b1f[nt] = *(const s16x8*)&B1s[(wn * 64 + nt * 16 + l16) * 64 +
                                              ((ks * 4 + quad) ^ (l16 & 7)) * 8];
                b2f[nt] = *(const s16x8*)&B2s[(wn * 64 + nt * 16 + l16) * 64 +
                                              ((ks * 4 + quad) ^ (l16 & 7)) * 8];
            }
#pragma unroll
            for (int mt = 0; mt < 4; ++mt)
#pragma unroll
                for (int nt = 0; nt < 4; ++nt) {
                    acc1[mt][nt] = __builtin_amdgcn_mfma_f32_16x16x32_bf16(af[mt], b1f[nt], acc1[mt][nt], 0, 0, 0);
                    acc2[mt][nt] = __builtin_amdgcn_mfma_f32_16x16x32_bf16(af[mt], b2f[nt], acc2[mt][nt], 0, 0, 0);
                }
        }
        __syncthreads();
    }

#pragma unroll
    for (int mt = 0; mt < 4; ++mt)
#pragma unroll
        for (int reg = 0; reg < 4; ++reg) {
            long row = m0 + wm * 64 + mt * 16 + quad * 4 + reg;
#pragma unroll
            for (int nt = 0; nt < 4; ++nt) {
                long col = n0 + wn * 64 + nt * 16 + l16;
                float g = acc1[mt][nt][reg];
                float s = g / (1.f + __expf(-g));
                outB[row * N + col] = f2bf(s * acc2[mt][nt][reg]);
            }
        }
}

// ---------------------------------------------------------------------------
// RoPE, vectorized: one block per (b,t) row; q scaled by 1/sqrt(D).
// qkv (B*T, 6144) bf16 -> qT/kT [bh][t][d].  Fast hw trig (__sinf/__cosf):
// bf16 output makes the ~2e-4 precision delta invisible.
// ---------------------------------------------------------------------------
__global__ __launch_bounds__(256) void rope_qk(
    const u16* __restrict__ qkv, u16* __restrict__ qT, u16* __restrict__ kT)
{
    const int row = blockIdx.x;
    const int t = row & 2047, b = row >> 11;
    const int tid = threadIdx.x;
    __shared__ u16 buf[4096];
    const u16* src = qkv + (long)row * 6144;
    u16x8 aa = *(const u16x8*)&src[tid * 8];
    u16x8 kk = *(const u16x8*)&src[2048 + tid * 8];
    *(u16x8*)&buf[tid * 8] = aa;
    *(u16x8*)&buf[2048 + tid * 8] = kk;
    __syncthreads();
    const int c = tid * 8;
    const int h = c >> 7, dh = c & 127;
    const bool first = dh < 64;
    const int pc = first ? (c + 64) : (c - 64);
    float cs[8], sn[8];
#pragma unroll
    for (int j = 0; j < 8; ++j) {
        float inv = __expf(-(float)((dh & 63) + j) * 0.14391156831212787f); // ln(1e4)/64
        float ang = (float)t * inv;
        cs[j] = __cosf(ang); sn[j] = __sinf(ang);
    }
    const long obase = ((long)(b * 16 + h) * 2048 + t) * 128 + dh;
#pragma unroll
    for (int part = 0; part < 2; ++part) {
        const int base = part * 2048;
        u16x8 mine = *(const u16x8*)&buf[base + c];
        u16x8 oth  = *(const u16x8*)&buf[base + pc];
        const float qs = part ? 1.f : 0.08838834764831845f;
        u16x8 o;
#pragma unroll
        for (int j = 0; j < 8; ++j) {
            float xv = bf2f(mine[j]), yv = bf2f(oth[j]);
            float ov = first ? (xv * cs[j] - yv * sn[j]) : (yv * sn[j] + xv * cs[j]);
            o[j] = f2bf(ov * qs);
        }
        u16* dst = part ? kT : qT;
        *(u16x8*)&dst[obase] = o;
    }
}

// ---------------------------------------------------------------------------
// v transpose: qkv v-part (b,t)(h,d) -> vT [bh][d][t].  LDS stride 65 (odd).
// ---------------------------------------------------------------------------
__global__ __launch_bounds__(256) void vtrans(
    const u16* __restrict__ qkv, u16* __restrict__ vT)
{
    const int bh = blockIdx.x;
    const int b = bh >> 4, h = bh & 15;
    const int t0 = blockIdx.y * 64, d0 = blockIdx.z * 64;
    __shared__ u16 tile[64 * 65];
    const int tid = threadIdx.x;
#pragma unroll
    for (int rr = 0; rr < 2; ++rr) {
        int idx = rr * 256 + tid;
        int r = idx >> 3, c = (idx & 7) * 8;
        u16x8 v = *(const u16x8*)&qkv[(long)(b * 2048 + t0 + r) * 6144 + 4096 + h * 128 + d0 + c];
#pragma unroll
        for (int j = 0; j < 8; ++j) tile[r * 65 + c + j] = v[j];
    }
    __syncthreads();
#pragma unroll
    for (int rr = 0; rr < 2; ++rr) {
        int idx = rr * 256 + tid;
        int dd = idx >> 3, cc = (idx & 7) * 8;
        u16x8 o;
#pragma unroll
        for (int j = 0; j < 8; ++j) o[j] = tile[(cc + j) * 65 + dd];
        *(u16x8*)&vT[((long)bh * 128 + d0 + dd) * 2048 + t0 + cc] = o;
    }
}

// ---------------------------------------------------------------------------
// Flash attention, causal. 1D grid 1024 blocks, 256 thr (4 waves, 16 q-rows
// each, QBLK=64). XCD-chunked swizzle (4 bh per XCD, heavy-qt-first).
// Double-buffered K/V, XOR-swizzled LDS, q pre-scaled by 1/sqrt(D).
// T13 defer-max + T5 setprio.
// ---------------------------------------------------------------------------
__global__ __launch_bounds__(256, 2) void attn_kernel(
    const u16* __restrict__ qT, const u16* __restrict__ kT,
    const u16* __restrict__ vT, u16* __restrict__ outT)
{
    const int T = 2048, D = 128;
    const int lid = blockIdx.x;
    const int swz = (lid & 7) * 128 + (lid >> 3);   // nwg=1024, chunk=128
    const int bh = swz >> 5;                        // 4 consecutive bh per XCD
    const int qt = 31 - (swz & 31);                 // heavy q-tiles first
    const int tid = threadIdx.x, lane = tid & 63, w = tid >> 6;
    const int quad = lane >> 4, l16 = lane & 15;
    const int qrow = qt * 64 + w * 16;

    __shared__ u16 Ks[2][64 * 128];
    __shared__ u16 Vs[2][128 * 64];
    __shared__ u16 Ps[4][16 * 64];

    s16x8 aq[4];
    const u16* qb = qT + ((long)bh * T + qrow + l16) * D;
#pragma unroll
    for (int kk = 0; kk < 4; ++kk)
        aq[kk] = *(const s16x8*)&qb[kk * 32 + quad * 8];

    f32x4 o[8] = {};
    float mi[4] = {-INFINITY, -INFINITY, -INFINITY, -INFINITY};
    float li[4] = {0.f, 0.f, 0.f, 0.f};

    const u16* kg0 = kT + (long)bh * T * D;
    const u16* vg0 = vT + (long)bh * D * T;

    auto stage = [&](int kt, int b) {
        const int k0 = kt * 64;
#pragma unroll
        for (int rr = 0; rr < 4; ++rr) {
            int idx = rr * 256 + tid;
            int kr = idx >> 4, kj = idx & 15;
            gl2lds16(kg0 + (long)(k0 + kr) * D + ((kj ^ (kr & 15)) * 8),
                     (char*)Ks[b] + idx * 16);
            int vr = idx >> 3, vj = idx & 7;
            gl2lds16(vg0 + (long)vr * T + k0 + ((vj ^ (vr & 7)) * 8),
                     (char*)Vs[b] + idx * 16);
        }
    };

    stage(0, 0);

    for (int kt = 0; kt <= qt; ++kt) {
        __syncthreads();                 // buf[kt&1] ready (loads had 1 full iter)
        if (kt < qt) stage(kt + 1, (kt + 1) & 1);
        const u16* ks_ = Ks[kt & 1];
        const u16* vs_ = Vs[kt & 1];
        const int k0 = kt * 64;

        // S = Q K^T
        f32x4 sf[4] = {};
        __builtin_amdgcn_s_setprio(1);
#pragma unroll
        for (int kk = 0; kk < 4; ++kk) {
#pragma unroll
            for (int nt = 0; nt < 4; ++nt) {
                s16x8 kb = *(const s16x8*)&ks_[(nt * 16 + l16) * 128 +
                                               ((kk * 4 + quad) ^ (l16 & 15)) * 8];
                sf[nt] = __builtin_amdgcn_mfma_f32_16x16x32_bf16(aq[kk], kb, sf[nt], 0, 0, 0);
            }
        }
        __builtin_amdgcn_s_setprio(0);

        float S[4][4];
        if (kt == qt) {   // diagonal tile: causal mask
#pragma unroll
            for (int nt = 0; nt < 4; ++nt) {
                int col = k0 + nt * 16 + l16;
#pragma unroll
                for (int reg = 0; reg < 4; ++reg) {
                    int row = qrow + quad * 4 + reg;
                    S[nt][reg] = (col <= row) ? sf[nt][reg] : -INFINITY;
                }
            }
        } else {
#pragma unroll
            for (int nt = 0; nt < 4; ++nt)
#pragma unroll
                for (int reg = 0; reg < 4; ++reg)
                    S[nt][reg] = sf[nt][reg];
        }

        float rm[4];
#pragma unroll
        for (int reg = 0; reg < 4; ++reg)
            rm[reg] = fmaxf(fmaxf(S[0][reg], S[1][reg]), fmaxf(S[2][reg], S[3][reg]));
#pragma unroll
        for (int m = 1; m < 16; m <<= 1)
#pragma unroll
            for (int reg = 0; reg < 4; ++reg)
                rm[reg] = fmaxf(rm[reg], __shfl_xor(rm[reg], m));

        // T13 defer-max: only rescale when the running max grew by > 8
        int cond = 1;
#pragma unroll
        for (int reg = 0; reg < 4; ++reg)
            cond &= (rm[reg] - mi[reg] <= 8.f) ? 1 : 0;
        if (!__all(cond)) {
            float alpha[4];
#pragma unroll
            for (int reg = 0; reg < 4; ++reg) {
                float mn = fmaxf(mi[reg], rm[reg]);
                alpha[reg] = __expf(mi[reg] - mn);
                mi[reg] = mn;
                li[reg] *= alpha[reg];
            }
#pragma unroll
            for (int dt = 0; dt < 8; ++dt)
#pragma unroll
                for (int reg = 0; reg < 4; ++reg)
                    o[dt][reg] *= alpha[reg];
        }

        float rs[4] = {};
#pragma unroll
        for (int nt = 0; nt < 4; ++nt)
#pragma unroll
            for (int reg = 0; reg < 4; ++reg) {
                float p = __expf(S[nt][reg] - mi[reg]);
                S[nt][reg] = p;
                rs[reg] += p;
            }
#pragma unroll
        for (int m = 1; m < 16; m <<= 1)
#pragma unroll
            for (int reg = 0; reg < 4; ++reg)
                rs[reg] += __shfl_xor(rs[reg], m);
#pragma unroll
        for (int reg = 0; reg < 4; ++reg)
            li[reg] += rs[reg];

        // P -> LDS, wave-private region (no barrier needed), XOR-swizzled
#pragma unroll
        for (int nt = 0; nt < 4; ++nt)
#pragma unroll
            for (int reg = 0; reg < 4; ++reg) {
                int prow = quad * 4 + reg;
                int pcol = nt * 16 + l16;
                Ps[w][prow * 64 + (((pcol >> 3) ^ (prow & 7)) * 8) + (pcol & 7)]
                    = f2bf(S[nt][reg]);
            }

        // O += P V   (Ps read: row l16, chunk ks*4+quad, swizzled)
        __builtin_amdgcn_s_setprio(1);
#pragma unroll
        for (int ks = 0; ks < 2; ++ks) {
            s16x8 pa = *(const s16x8*)&Ps[w][l16 * 64 +
                                             ((ks * 4 + quad) ^ (l16 & 7)) * 8];
#pragma unroll
            for (int dt = 0; dt < 8; ++dt) {
                s16x8 vb = *(const s16x8*)&vs_[(dt * 16 + l16) * 64 +
                                               ((ks * 4 + quad) ^ (l16 & 7)) * 8];
                o[dt] = __builtin_amdgcn_mfma_f32_16x16x32_bf16(pa, vb, o[dt], 0, 0, 0);
            }
        }
        __builtin_amdgcn_s_setprio(0);
    }

    const int b = bh >> 4, h = bh & 15;
#pragma unroll
    for (int reg = 0; reg < 4; ++reg) {
        float inv = 1.f / li[reg];
        int t = qrow + quad * 4 + reg;
        u16* orow = outT + ((long)(b * T + t)) * 2048 + h * 128;
#pragma unroll
        for (int dt = 0; dt < 8; ++dt)
            orow[dt * 16 + l16] = f2bf(o[dt][reg] * inv);
    }
}

// ---------------------------------------------------------------------------
// Workspace layout (188 MiB total, unions by live-range):
//   Z 24 MiB: wqkv_t -> w3_t | wproj 8 | w1_t 22 | w2_t 22
//   C 16 MiB: h -> attn_out -> h2 | D 48 MiB: qkv -> u | E 48 MiB: q/k/vT -> x2
// ---------------------------------------------------------------------------
extern "C" void kernel_launch(void* const* d_in, const int* in_sizes, int n_in,
                              void* d_out, int out_size, void* d_ws, size_t ws_size,
                              hipStream_t stream) {
    const float* x      = (const float*)d_in[0];
    const float* wn1    = (const float*)d_in[1];
    const float* w_qkv  = (const float*)d_in[2];
    const float* w_proj = (const float*)d_in[3];
    const float* wn2    = (const float*)d_in[4];
    const float* w1     = (const float*)d_in[5];
    const float* w2     = (const float*)d_in[6];
    const float* w3     = (const float*)d_in[7];
    float* out = (float*)d_out;

    char* p = (char*)d_ws;
    u16* Z       = (u16*)p; p += (size_t)6144 * 2048 * 2;
    u16* wproj_t = (u16*)p; p += (size_t)2048 * 2048 * 2;
    u16* w1_t    = (u16*)p; p += (size_t)5632 * 2048 * 2;
    u16* w2_t    = (u16*)p; p += (size_t)5632 * 2048 * 2;
    u16* C       = (u16*)p; p += (size_t)4096 * 2048 * 2;
    u16* D       = (u16*)p; p += (size_t)4096 * 6144 * 2;
    u16* E       = (u16*)p; p += (size_t)3 * 32 * 2048 * 128 * 2;

    u16* wqkv_t = Z;
    u16* w3_t   = Z;
    u16* qT = E;
    u16* kT = E + (size_t)32 * 2048 * 128;
    u16* vT = E + (size_t)2 * 32 * 2048 * 128;
    float* x2 = (float*)E;
    u16* uu = D;

    // 4 independent weight transposes in ONE launch (w3 excluded: aliases Z)
    tcast4<<<38912, 256, 0, stream>>>(w_qkv, w_proj, w1, w2,
                                      wqkv_t, wproj_t, w1_t, w2_t);

    rmsnorm_cast<<<4096, 256, 0, stream>>>(x, wn1, C);
    gemm128<0><<<dim3(32, 48), 256, 0, stream>>>(C, wqkv_t, 6144, 2048,
                                                 nullptr, D, nullptr);
    rope_qk<<<4096, 256, 0, stream>>>(D, qT, kT);
    vtrans<<<dim3(32, 32, 2), 256, 0, stream>>>(D, vT);

    tcast<<<dim3(176, 64), 256, 0, stream>>>(w3, w3_t, 5632, 2048);

    attn_kernel<<<1024, 256, 0, stream>>>(qT, kT, vT, C);

    gemm128<1><<<dim3(32, 16), 256, 0, stream>>>(C, wproj_t, 2048, 2048,
                                                 x2, nullptr, x);
    rmsnorm_cast<<<4096, 256, 0, stream>>>(x2, wn2, C);
    gemm_ffn<<<dim3(32, 44), 256, 0, stream>>>(C, w1_t, w2_t, 5632, 2048, uu);
    gemm128<1><<<dim3(32, 16), 256, 0, stream>>>(uu, w3_t, 2048, 5632,
                                                 out, nullptr, x2);
}

// Round 8
// 831.662 us; speedup vs baseline: 1.0662x; 1.0072x over previous
//
#include <hip/hip_runtime.h>

typedef short s16x8 __attribute__((ext_vector_type(8)));
typedef unsigned short u16;
typedef u16 u16x8 __attribute__((ext_vector_type(8)));
typedef u16 u16x4 __attribute__((ext_vector_type(4)));
typedef float f32x4 __attribute__((ext_vector_type(4)));

#define DEVINL __device__ __forceinline__

DEVINL u16 f2bf(float f) {
    unsigned u = __float_as_uint(f);
    u += 0x7FFFu + ((u >> 16) & 1u);
    return (u16)(u >> 16);
}
DEVINL float bf2f(u16 h) { return __uint_as_float((unsigned)h << 16); }

DEVINL void gl2lds16(const void* g, void* l) {
    __builtin_amdgcn_global_load_lds((const __attribute__((address_space(1))) void*)g,
                                     (__attribute__((address_space(3))) void*)l, 16, 0, 0);
}

// ---------------------------------------------------------------------------
// Transpose-cast tile: src (K,N) fp32 rm -> dst (N,K) bf16 rm, one 32x32 tile.
// ---------------------------------------------------------------------------
DEVINL void tcast_tile(const float* __restrict__ src, u16* __restrict__ dst,
                       const int K, const int N, const int kx, const int ny,
                       const int tid, float (*tile)[33])
{
    const long k0 = (long)kx * 32;
    const long n0 = (long)ny * 32;
    const int r = tid >> 3, c4 = (tid & 7) * 4;
    float4 v = *(const float4*)&src[(k0 + r) * N + n0 + c4];
    tile[r][c4] = v.x; tile[r][c4 + 1] = v.y; tile[r][c4 + 2] = v.z; tile[r][c4 + 3] = v.w;
    __syncthreads();
    u16x4 ov;
    ov[0] = f2bf(tile[c4][r]);     ov[1] = f2bf(tile[c4 + 1][r]);
    ov[2] = f2bf(tile[c4 + 2][r]); ov[3] = f2bf(tile[c4 + 3][r]);
    *(u16x4*)&dst[(n0 + r) * K + k0 + c4] = ov;
}

// ---------------------------------------------------------------------------
// RMSNorm row (C=2048) fp32 -> bf16 (shared: 16B scratch inside tile buffer)
// ---------------------------------------------------------------------------
DEVINL void rmsnorm_row(const float* __restrict__ x, const float* __restrict__ wn,
                        u16* __restrict__ out, const long row, const int tid,
                        float* red)
{
    const int C = 2048;
    const float4* xr = (const float4*)(x + row * C);
    float4 a = xr[tid * 2], b = xr[tid * 2 + 1];
    float ss = a.x*a.x + a.y*a.y + a.z*a.z + a.w*a.w
             + b.x*b.x + b.y*b.y + b.z*b.z + b.w*b.w;
#pragma unroll
    for (int m = 1; m < 64; m <<= 1) ss += __shfl_xor(ss, m);
    if ((tid & 63) == 0) red[tid >> 6] = ss;
    __syncthreads();
    float scale = rsqrtf((red[0] + red[1] + red[2] + red[3]) * (1.f / 2048.f) + 1e-6f);
    const float4* wr = (const float4*)wn;
    float4 wa = wr[tid * 2], wb = wr[tid * 2 + 1];
    u16x8 o;
    o[0] = f2bf(a.x * scale * wa.x); o[1] = f2bf(a.y * scale * wa.y);
    o[2] = f2bf(a.z * scale * wa.z); o[3] = f2bf(a.w * scale * wa.w);
    o[4] = f2bf(b.x * scale * wb.x); o[5] = f2bf(b.y * scale * wb.y);
    o[6] = f2bf(b.z * scale * wb.z); o[7] = f2bf(b.w * scale * wb.w);
    *(u16x8*)&out[row * C + tid * 8] = o;
}

// Standalone rmsnorm (for the second norm, mid-pipeline)
__global__ __launch_bounds__(256) void rmsnorm_cast(
    const float* __restrict__ x, const float* __restrict__ wn, u16* __restrict__ out)
{
    __shared__ float red[4];
    rmsnorm_row(x, wn, out, blockIdx.x, threadIdx.x, red);
}

// ---------------------------------------------------------------------------
// prep0: ONE launch = rmsnorm1 (4096 rows) + 4 weight transposes (38912 tiles)
// ---------------------------------------------------------------------------
__global__ __launch_bounds__(256) void prep0(
    const float* __restrict__ x, const float* __restrict__ wn1, u16* __restrict__ h,
    const float* __restrict__ s0, const float* __restrict__ s1,
    const float* __restrict__ s2, const float* __restrict__ s3,
    u16* __restrict__ d0, u16* __restrict__ d1,
    u16* __restrict__ d2, u16* __restrict__ d3)
{
    __shared__ float tile[32][33];
    int t = blockIdx.x;
    if (t < 4096) {
        rmsnorm_row(x, wn1, h, t, threadIdx.x, &tile[0][0]);
        return;
    }
    t -= 4096;
    const float* src; u16* dst; int N;
    if (t < 12288)      {             src = s0; dst = d0; N = 6144; }
    else if (t < 16384) { t -= 12288; src = s1; dst = d1; N = 2048; }
    else if (t < 27648) { t -= 16384; src = s2; dst = d2; N = 5632; }
    else                { t -= 27648; src = s3; dst = d3; N = 5632; }
    tcast_tile(src, dst, 2048, N, t & 63, t >> 6, threadIdx.x, tile);
}

// ---------------------------------------------------------------------------
// GEMM BK=128: A (M x K) bf16 rm, Bt (N x K) bf16 rm, 128x128 tile, 256 thr.
// Half the barriers of BK=64. LDS 64 KiB (2 blocks/CU kept — reg-bound anyway).
// 16-chunk XOR swizzle (attn-Ks proven): chunk j of row r at slot j^(r&15).
// MODE 0: outB = bf16(acc)   MODE 1: outF = resid + acc (fp32)
// ---------------------------------------------------------------------------
template <int MODE>
__global__ __launch_bounds__(256, 2) void gemm128k(
    const u16* __restrict__ A, const u16* __restrict__ Bt,
    const int N, const int K,
    float* __restrict__ outF, u16* __restrict__ outB,
    const float* __restrict__ resid)
{
    __shared__ u16 As[128 * 128];
    __shared__ u16 Bs[128 * 128];
    const int tid = threadIdx.x;
    const int lane = tid & 63;
    const int w = tid >> 6;
    const int wm = w >> 1, wn = w & 1;
    const int quad = lane >> 4, l16 = lane & 15;
    const long m0 = (long)blockIdx.x * 128;
    const long n0 = (long)blockIdx.y * 128;

    const int r0 = tid >> 4;                   // 0..15 (16 thr/row, 16 chunks)
    const int c0 = ((tid & 15) ^ r0) * 8;      // XOR source-swizzle; r&15 == r0 for all rounds
    const u16* gA = A + (m0 + r0) * K + c0;
    const u16* gB = Bt + (n0 + r0) * K + c0;
    char* lA = (char*)As + tid * 16;
    char* lB = (char*)Bs + tid * 16;
    const long rstep = (long)16 * K;           // 16 rows per staging round

    f32x4 acc[4][4] = {};

    for (int k0 = 0; k0 < K; k0 += 128) {
#pragma unroll
        for (int rr = 0; rr < 8; ++rr) {
            gl2lds16(gA + k0 + rr * rstep, lA + rr * 4096);
            gl2lds16(gB + k0 + rr * rstep, lB + rr * 4096);
        }
        __syncthreads();
#pragma unroll
        for (int ks = 0; ks < 4; ++ks) {
            s16x8 af[4], bfv[4];
#pragma unroll
            for (int mt = 0; mt < 4; ++mt)
                af[mt] = *(const s16x8*)&As[(wm * 64 + mt * 16 + l16) * 128 +
                                            ((ks * 4 + quad) ^ l16) * 8];
#pragma unroll
            for (int nt = 0; nt < 4; ++nt)
                bfv[nt] = *(const s16x8*)&Bs[(wn * 64 + nt * 16 + l16) * 128 +
                                             ((ks * 4 + quad) ^ l16) * 8];
#pragma unroll
            for (int mt = 0; mt < 4; ++mt)
#pragma unroll
                for (int nt = 0; nt < 4; ++nt)
                    acc[mt][nt] = __builtin_amdgcn_mfma_f32_16x16x32_bf16(af[mt], bfv[nt], acc[mt][nt], 0, 0, 0);
        }
        __syncthreads();
    }

#pragma unroll
    for (int mt = 0; mt < 4; ++mt)
#pragma unroll
        for (int reg = 0; reg < 4; ++reg) {
            long row = m0 + wm * 64 + mt * 16 + quad * 4 + reg;
#pragma unroll
            for (int nt = 0; nt < 4; ++nt) {
                long col = n0 + wn * 64 + nt * 16 + l16;
                float v = acc[mt][nt][reg];
                if (MODE == 0) {
                    outB[row * N + col] = f2bf(v);
                } else {
                    outF[row * N + col] = resid[row * N + col] + v;
                }
            }
        }
}

// ---------------------------------------------------------------------------
// Fused FFN up-projection (BK=64, 3 operands: 96KiB at BK=128 would drop to
// 1 block/CU — the m132 trap — so this stays at the proven structure).
// u = bf16( silu(A@B1t^T) * (A@B2t^T) )
// ---------------------------------------------------------------------------
__global__ __launch_bounds__(256, 2) void gemm_ffn(
    const u16* __restrict__ A, const u16* __restrict__ B1t, const u16* __restrict__ B2t,
    const int N, const int K, u16* __restrict__ outB)
{
    __shared__ u16 As[128 * 64];
    __shared__ u16 B1s[128 * 64];
    __shared__ u16 B2s[128 * 64];
    const int tid = threadIdx.x;
    const int lane = tid & 63;
    const int w = tid >> 6;
    const int wm = w >> 1, wn = w & 1;
    const int quad = lane >> 4, l16 = lane & 15;
    const long m0 = (long)blockIdx.x * 128;
    const long n0 = (long)blockIdx.y * 128;

    const u16* ga[4]; const u16* gb1[4]; const u16* gb2[4];
    char* la[4]; char* lb1[4]; char* lb2[4];
#pragma unroll
    for (int rr = 0; rr < 4; ++rr) {
        int idx = rr * 256 + tid;
        int r = idx >> 3, j = idx & 7;
        int c = (j ^ (r & 7)) * 8;
        ga[rr]  = A + (m0 + r) * K + c;
        gb1[rr] = B1t + (n0 + r) * K + c;
        gb2[rr] = B2t + (n0 + r) * K + c;
        la[rr]  = (char*)As + idx * 16;
        lb1[rr] = (char*)B1s + idx * 16;
        lb2[rr] = (char*)B2s + idx * 16;
    }

    f32x4 acc1[4][4] = {};
    f32x4 acc2[4][4] = {};

    for (int k0 = 0; k0 < K; k0 += 64) {
#pragma unroll
        for (int rr = 0; rr < 4; ++rr) {
            gl2lds16(ga[rr] + k0, la[rr]);
            gl2lds16(gb1[rr] + k0, lb1[rr]);
            gl2lds16(gb2[rr] + k0, lb2[rr]);
        }
        __syncthreads();
#pragma unroll
        for (int ks = 0; ks < 2; ++ks) {
            s16x8 af[4], b1f[4], b2f[4];
#pragma unroll
            for (int mt = 0; mt < 4; ++mt)
                af[mt] = *(const s16x8*)&As[(wm * 64 + mt * 16 + l16) * 64 +
                                            ((ks * 4 + quad) ^ (l16 & 7)) * 8];
#pragma unroll
            for (int nt = 0; nt < 4; ++nt) {
                b1f[nt] = *(const s16x8*)&B1s[(wn * 64 + nt * 16 + l16) * 64 +
                                              ((ks * 4 + quad) ^ (l16 & 7)) * 8];
                b2f[nt] = *(const s16x8*)&B2s[(wn * 64 + nt * 16 + l16) * 64 +
                                              ((ks * 4 + quad) ^ (l16 & 7)) * 8];
            }
#pragma unroll
            for (int mt = 0; mt < 4; ++mt)
#pragma unroll
                for (int nt = 0; nt < 4; ++nt) {
                    acc1[mt][nt] = __builtin_amdgcn_mfma_f32_16x16x32_bf16(af[mt], b1f[nt], acc1[mt][nt], 0, 0, 0);
                    acc2[mt][nt] = __builtin_amdgcn_mfma_f32_16x16x32_bf16(af[mt], b2f[nt], acc2[mt][nt], 0, 0, 0);
                }
        }
        __syncthreads();
    }

#pragma unroll
    for (int mt = 0; mt < 4; ++mt)
#pragma unroll
        for (int reg = 0; reg < 4; ++reg) {
            long row = m0 + wm * 64 + mt * 16 + quad * 4 + reg;
#pragma unroll
            for (int nt = 0; nt < 4; ++nt) {
                long col = n0 + wn * 64 + nt * 16 + l16;
                float g = acc1[mt][nt][reg];
                float s = g / (1.f + __expf(-g));
                outB[row * N + col] = f2bf(s * acc2[mt][nt][reg]);
            }
        }
}

// ---------------------------------------------------------------------------
// ropev: ONE launch = RoPE q/k (4096) + v transpose (2048) + w3 tcast (11264).
// w3_t aliases wqkv_t, dead after the qkv GEMM which precedes this launch.
// ---------------------------------------------------------------------------
__global__ __launch_bounds__(256) void ropev(
    const u16* __restrict__ qkv, u16* __restrict__ qT, u16* __restrict__ kT,
    u16* __restrict__ vT, const float* __restrict__ w3, u16* __restrict__ w3t)
{
    __shared__ float smf[2080];   // 8320 B, shared by all three branches
    const int t = blockIdx.x;
    const int tid = threadIdx.x;

    if (t < 4096) {
        // ---- RoPE on q,k; q pre-scaled by 1/sqrt(D). hw trig. ----
        u16* buf = (u16*)smf;     // 4096 u16
        const int trow = t & 2047, b = t >> 11;
        const u16* src = qkv + (long)t * 6144;
        u16x8 aa = *(const u16x8*)&src[tid * 8];
        u16x8 kk = *(const u16x8*)&src[2048 + tid * 8];
        *(u16x8*)&buf[tid * 8] = aa;
        *(u16x8*)&buf[2048 + tid * 8] = kk;
        __syncthreads();
        const int c = tid * 8;
        const int h = c >> 7, dh = c & 127;
        const bool first = dh < 64;
        const int pc = first ? (c + 64) : (c - 64);
        float cs[8], sn[8];
#pragma unroll
        for (int j = 0; j < 8; ++j) {
            float inv = __expf(-(float)((dh & 63) + j) * 0.14391156831212787f); // ln(1e4)/64
            float ang = (float)trow * inv;
            cs[j] = __cosf(ang); sn[j] = __sinf(ang);
        }
        const long obase = ((long)(b * 16 + h) * 2048 + trow) * 128 + dh;
#pragma unroll
        for (int part = 0; part < 2; ++part) {
            const int base = part * 2048;
            u16x8 mine = *(const u16x8*)&buf[base + c];
            u16x8 oth  = *(const u16x8*)&buf[base + pc];
            const float qs = part ? 1.f : 0.08838834764831845f;
            u16x8 o;
#pragma unroll
            for (int j = 0; j < 8; ++j) {
                float xv = bf2f(mine[j]), yv = bf2f(oth[j]);
                float ov = first ? (xv * cs[j] - yv * sn[j]) : (yv * sn[j] + xv * cs[j]);
                o[j] = f2bf(ov * qs);
            }
            u16* dst = part ? kT : qT;
            *(u16x8*)&dst[obase] = o;
        }
    } else if (t < 6144) {
        // ---- v transpose: (b,t)(h,d) -> vT [bh][d][t], LDS stride 65 ----
        u16* tile = (u16*)smf;    // 64*65 u16 = 8320 B
        const int u = t - 4096;
        const int bh = u & 31;
        const int b = bh >> 4, h = bh & 15;
        const int t0 = ((u >> 5) & 31) * 64, d0 = (u >> 10) * 64;
#pragma unroll
        for (int rr = 0; rr < 2; ++rr) {
            int idx = rr * 256 + tid;
            int r = idx >> 3, c = (idx & 7) * 8;
            u16x8 v = *(const u16x8*)&qkv[(long)(b * 2048 + t0 + r) * 6144 + 4096 + h * 128 + d0 + c];
#pragma unroll
            for (int j = 0; j < 8; ++j) tile[r * 65 + c + j] = v[j];
        }
        __syncthreads();
#pragma unroll
        for (int rr = 0; rr < 2; ++rr) {
            int idx = rr * 256 + tid;
            int dd = idx >> 3, cc = (idx & 7) * 8;
            u16x8 o;
#pragma unroll
            for (int j = 0; j < 8; ++j) o[j] = tile[(cc + j) * 65 + dd];
            *(u16x8*)&vT[((long)bh * 128 + d0 + dd) * 2048 + t0 + cc] = o;
        }
    } else {
        // ---- w3 transpose-cast: (5632, 2048) fp32 -> (2048, 5632) bf16 ----
        const int v = t - 6144;             // 0..11263, grid was (176, 64)
        const int kx = v % 176, ny = v / 176;
        tcast_tile(w3, w3t, 5632, 2048, kx, ny, tid, (float (*)[33])smf);
    }
}

// ---------------------------------------------------------------------------
// Flash attention, causal. 1D grid 1024 blocks, 256 thr (4 waves, 16 q-rows
// each, QBLK=64). XCD-chunked swizzle (4 bh per XCD, heavy-qt-first).
// Double-buffered K/V, XOR-swizzled LDS, q pre-scaled by 1/sqrt(D).
// T13 defer-max + T5 setprio.
// ---------------------------------------------------------------------------
__global__ __launch_bounds__(256, 2) void attn_kernel(
    const u16* __restrict__ qT, const u16* __restrict__ kT,
    const u16* __restrict__ vT, u16* __restrict__ outT)
{
    const int T = 2048, D = 128;
    const int lid = blockIdx.x;
    const int swz = (lid & 7) * 128 + (lid >> 3);   // nwg=1024, chunk=128
    const int bh = swz >> 5;                        // 4 consecutive bh per XCD
    const int qt = 31 - (swz & 31);                 // heavy q-tiles first
    const int tid = threadIdx.x, lane = tid & 63, w = tid >> 6;
    const int quad = lane >> 4, l16 = lane & 15;
    const int qrow = qt * 64 + w * 16;

    __shared__ u16 Ks[2][64 * 128];
    __shared__ u16 Vs[2][128 * 64];
    __shared__ u16 Ps[4][16 * 64];

    s16x8 aq[4];
    const u16* qb = qT + ((long)bh * T + qrow + l16) * D;
#pragma unroll
    for (int kk = 0; kk < 4; ++kk)
        aq[kk] = *(const s16x8*)&qb[kk * 32 + quad * 8];

    f32x4 o[8] = {};
    float mi[4] = {-INFINITY, -INFINITY, -INFINITY, -INFINITY};
    float li[4] = {0.f, 0.f, 0.f, 0.f};

    const u16* kg0 = kT + (long)bh * T * D;
    const u16* vg0 = vT + (long)bh * D * T;

    auto stage = [&](int kt, int b) {
        const int k0 = kt * 64;
#pragma unroll
        for (int rr = 0; rr < 4; ++rr) {
            int idx = rr * 256 + tid;
            int kr = idx >> 4, kj = idx & 15;
            gl2lds16(kg0 + (long)(k0 + kr) * D + ((kj ^ (kr & 15)) * 8),
                     (char*)Ks[b] + idx * 16);
            int vr = idx >> 3, vj = idx & 7;
            gl2lds16(vg0 + (long)vr * T + k0 + ((vj ^ (vr & 7)) * 8),
                     (char*)Vs[b] + idx * 16);
        }
    };

    stage(0, 0);

    for (int kt = 0; kt <= qt; ++kt) {
        __syncthreads();                 // buf[kt&1] ready (loads had 1 full iter)
        if (kt < qt) stage(kt + 1, (kt + 1) & 1);
        const u16* ks_ = Ks[kt & 1];
        const u16* vs_ = Vs[kt & 1];
        const int k0 = kt * 64;

        // S = Q K^T
        f32x4 sf[4] = {};
        __builtin_amdgcn_s_setprio(1);
#pragma unroll
        for (int kk = 0; kk < 4; ++kk) {
#pragma unroll
            for (int nt = 0; nt < 4; ++nt) {
                s16x8 kb = *(const s16x8*)&ks_[(nt * 16 + l16) * 128 +
                                               ((kk * 4 + quad) ^ (l16 & 15)) * 8];
                sf[nt] = __builtin_amdgcn_mfma_f32_16x16x32_bf16(aq[kk], kb, sf[nt], 0, 0, 0);
            }
        }
        __builtin_amdgcn_s_setprio(0);

        float S[4][4];
        if (kt == qt) {   // diagonal tile: causal mask
#pragma unroll
            for (int nt = 0; nt < 4; ++nt) {
                int col = k0 + nt * 16 + l16;
#pragma unroll
                for (int reg = 0; reg < 4; ++reg) {
                    int row = qrow + quad * 4 + reg;
                    S[nt][reg] = (col <= row) ? sf[nt][reg] : -INFINITY;
                }
            }
        } else {
#pragma unroll
            for (int nt = 0; nt < 4; ++nt)
#pragma unroll
                for (int reg = 0; reg < 4; ++reg)
                    S[nt][reg] = sf[nt][reg];
        }

        float rm[4];
#pragma unroll
        for (int reg = 0; reg < 4; ++reg)
            rm[reg] = fmaxf(fmaxf(S[0][reg], S[1][reg]), fmaxf(S[2][reg], S[3][reg]));
#pragma unroll
        for (int m = 1; m < 16; m <<= 1)
#pragma unroll
            for (int reg = 0; reg < 4; ++reg)
                rm[reg] = fmaxf(rm[reg], __shfl_xor(rm[reg], m));

        // T13 defer-max: only rescale when the running max grew by > 8
        int cond = 1;
#pragma unroll
        for (int reg = 0; reg < 4; ++reg)
            cond &= (rm[reg] - mi[reg] <= 8.f) ? 1 : 0;
        if (!__all(cond)) {
            float alpha[4];
#pragma unroll
            for (int reg = 0; reg < 4; ++reg) {
                float mn = fmaxf(mi[reg], rm[reg]);
                alpha[reg] = __expf(mi[reg] - mn);
                mi[reg] = mn;
                li[reg] *= alpha[reg];
            }
#pragma unroll
            for (int dt = 0; dt < 8; ++dt)
#pragma unroll
                for (int reg = 0; reg < 4; ++reg)
                    o[dt][reg] *= alpha[reg];
        }

        float rs[4] = {};
#pragma unroll
        for (int nt = 0; nt < 4; ++nt)
#pragma unroll
            for (int reg = 0; reg < 4; ++reg) {
                float p = __expf(S[nt][reg] - mi[reg]);
                S[nt][reg] = p;
                rs[reg] += p;
            }
#pragma unroll
        for (int m = 1; m < 16; m <<= 1)
#pragma unroll
            for (int reg = 0; reg < 4; ++reg)
                rs[reg] += __shfl_xor(rs[reg], m);
#pragma unroll
        for (int reg = 0; reg < 4; ++reg)
            li[reg] += rs[reg];

        // P -> LDS, wave-private region (no barrier needed), XOR-swizzled
#pragma unroll
        for (int nt = 0; nt < 4; ++nt)
#pragma unroll
            for (int reg = 0; reg < 4; ++reg) {
                int prow = quad * 4 + reg;
                int pcol = nt * 16 + l16;
                Ps[w][prow * 64 + (((pcol >> 3) ^ (prow & 7)) * 8) + (pcol & 7)]
                    = f2bf(S[nt][reg]);
            }

        // O += P V   (Ps read: row l16, chunk ks*4+quad, swizzled)
        __builtin_amdgcn_s_setprio(1);
#pragma unroll
        for (int ks = 0; ks < 2; ++ks) {
            s16x8 pa = *(const s16x8*)&Ps[w][l16 * 64 +
                                             ((ks * 4 + quad) ^ (l16 & 7)) * 8];
#pragma unroll
            for (int dt = 0; dt < 8; ++dt) {
                s16x8 vb = *(const s16x8*)&vs_[(dt * 16 + l16) * 64 +
                                               ((ks * 4 + quad) ^ (l16 & 7)) * 8];
                o[dt] = __builtin_amdgcn_mfma_f32_16x16x32_bf16(pa, vb, o[dt], 0, 0, 0);
            }
        }
        __builtin_amdgcn_s_setprio(0);
    }

    const int b = bh >> 4, h = bh & 15;
#pragma unroll
    for (int reg = 0; reg < 4; ++reg) {
        float inv = 1.f / li[reg];
        int t = qrow + quad * 4 + reg;
        u16* orow = outT + ((long)(b * T + t)) * 2048 + h * 128;
#pragma unroll
        for (int dt = 0; dt < 8; ++dt)
            orow[dt * 16 + l16] = f2bf(o[dt][reg] * inv);
    }
}

// ---------------------------------------------------------------------------
// Workspace layout (188 MiB total, unions by live-range):
//   Z 24 MiB: wqkv_t -> w3_t | wproj 8 | w1_t 22 | w2_t 22
//   C 16 MiB: h -> attn_out -> h2 | D 48 MiB: qkv -> u | E 48 MiB: q/k/vT -> x2
// ---------------------------------------------------------------------------
extern "C" void kernel_launch(void* const* d_in, const int* in_sizes, int n_in,
                              void* d_out, int out_size, void* d_ws, size_t ws_size,
                              hipStream_t stream) {
    const float* x      = (const float*)d_in[0];
    const float* wn1    = (const float*)d_in[1];
    const float* w_qkv  = (const float*)d_in[2];
    const float* w_proj = (const float*)d_in[3];
    const float* wn2    = (const float*)d_in[4];
    const float* w1     = (const float*)d_in[5];
    const float* w2     = (const float*)d_in[6];
    const float* w3     = (const float*)d_in[7];
    float* out = (float*)d_out;

    char* p = (char*)d_ws;
    u16* Z       = (u16*)p; p += (size_t)6144 * 2048 * 2;
    u16* wproj_t = (u16*)p; p += (size_t)2048 * 2048 * 2;
    u16* w1_t    = (u16*)p; p += (size_t)5632 * 2048 * 2;
    u16* w2_t    = (u16*)p; p += (size_t)5632 * 2048 * 2;
    u16* C       = (u16*)p; p += (size_t)4096 * 2048 * 2;
    u16* D       = (u16*)p; p += (size_t)4096 * 6144 * 2;
    u16* E       = (u16*)p; p += (size_t)3 * 32 * 2048 * 128 * 2;

    u16* wqkv_t = Z;
    u16* w3_t   = Z;
    u16* qT = E;
    u16* kT = E + (size_t)32 * 2048 * 128;
    u16* vT = E + (size_t)2 * 32 * 2048 * 128;
    float* x2 = (float*)E;
    u16* uu = D;

    // rmsnorm1 + 4 weight transposes, ONE launch
    prep0<<<43008, 256, 0, stream>>>(x, wn1, C,
                                     w_qkv, w_proj, w1, w2,
                                     wqkv_t, wproj_t, w1_t, w2_t);

    gemm128k<0><<<dim3(32, 48), 256, 0, stream>>>(C, wqkv_t, 6144, 2048,
                                                  nullptr, D, nullptr);

    // rope q/k + v transpose + w3 transpose (Z free after qkv GEMM), ONE launch
    ropev<<<17408, 256, 0, stream>>>(D, qT, kT, vT, w3, w3_t);

    attn_kernel<<<1024, 256, 0, stream>>>(qT, kT, vT, C);

    gemm128k<1><<<dim3(32, 16), 256, 0, stream>>>(C, wproj_t, 2048, 2048,
                                                  x2, nullptr, x);
    rmsnorm_cast<<<4096, 256, 0, stream>>>(x2, wn2, C);
    gemm_ffn<<<dim3(32, 44), 256, 0, stream>>>(C, w1_t, w2_t, 5632, 2048, uu);
    gemm128k<1><<<dim3(32, 16), 256, 0, stream>>>(uu, w3_t, 2048, 5632,
                                                  out, nullptr, x2);
}